// Round 6
// baseline (261.861 us; speedup 1.0000x reference)
//
#include <hip/hip_runtime.h>

// GCN layer: out = relu( segment_mean(feature[edge_src], edge_dst) @ W^T + b )
// N=100000 nodes, E=1200000 edges, 64 feats in/out, all f32.
//
// Round 20: globally bucket-sorted edges via global-atomic append.
// Rationale: with all dispatches <44us and counters (when last visible)
// showing no pipe >40%, the cost is serial phase chains. The per-build-block
// edge grouping forced aggregate to run a 512-load segment map + 256-wide
// scan + an 8-step dependent-LDS binary search per edge word (16 serialized
// ds_reads/thread) before gathering. Phase-4 sums are order-independent
// (fixed-point int adds commute), so edge order within a bucket is free:
//  * K0 prep: zero gcnt[2048], convert W -> global bf16 table (8KB, L2-hot).
//  * K1 build: feature f32->bf16 uint4 rows (as r19) + one-pass edge scatter:
//    pos = atomicAdd(&gcnt[bk],1); gsorted[bk*768+pos] = src|dL<<17.
//    No LDS, no scan, no offTT, no register edge cache.
//  * K2 aggregate: sz = gcnt[bkt]; edges read as ONE contiguous range.
//    Keeps r19's src-window re-sort (L2-friendly sweep), fixed-point LDS
//    atomic gather, MFMA epilogue (B-frags straight from global W table).
// Output bit-identical to r19 (commutative sums, exact degrees).

typedef __attribute__((ext_vector_type(8))) short short8;   // 8 bf16
typedef __attribute__((ext_vector_type(4))) float floatx4;  // MFMA acc

constexpr int kNodes = 100000;
constexpr int kEdges = 1200000;

constexpr int kBuckets = 2048;
constexpr int kBucketNodes = 49;                    // 2048*49 = 100352 >= N

constexpr int kCap = 768;         // max edges/bucket (mean 586, ~7.5 sigma)
constexpr float kFxScale = 262144.0f;   // 2^18 fixed-point scale
constexpr int kAccStride = 68;    // 16B-aligned rows; adds at {c,8+c,...,56+c}

// Workspace layout (int elements). Total ~19.1 MB.
constexpr int kWsFeat   = 0;                        // uint4[100000*8] (12.8MB)
constexpr int kWsCnt    = 3200000;                  // int[2048]
constexpr int kWsWb     = 3202048;                  // 4096 bf16 (8KB)
constexpr int kWsSorted = 3204096;                  // int[2048*768] (6MB)

__device__ __forceinline__ unsigned bf16rne(float f) {
  unsigned u = __float_as_uint(f);
  return (u + 0x7fffu + ((u >> 16) & 1u)) >> 16;  // round-to-nearest-even
}

// ---------------------------------------------------------------------------
// Kernel 0: zero bucket counters + W f32 -> bf16 global table.
// ---------------------------------------------------------------------------
__global__ __launch_bounds__(512) void gcn_prep(
    const float* __restrict__ W, int* __restrict__ ws) {
  int* gcnt = ws + kWsCnt;
  ushort* Wb16g = (ushort*)(ws + kWsWb);
  const int t = blockIdx.x * 512 + threadIdx.x;   // 4 blocks -> 2048 threads
  gcnt[t] = 0;
  Wb16g[t]        = (ushort)bf16rne(W[t]);
  Wb16g[t + 2048] = (ushort)bf16rne(W[t + 2048]);
}

// ---------------------------------------------------------------------------
// Kernel 1: feature conversion + one-pass global bucket scatter.
// Conversion: permuted bf16 rows as uint4[8] per node — halfword w of chunk c
// stores feat[8*w + c], so each 16B chunk c = feats {c,8+c,...,56+c}.
// Scatter: bucket = dst/49; global append via atomicAdd on gcnt.
// ---------------------------------------------------------------------------
__global__ __launch_bounds__(256) void gcn_build(
    const float* __restrict__ feat,
    const int* __restrict__ src, const int* __restrict__ dst,
    int* __restrict__ ws) {
  uint4* fb16  = (uint4*)(ws + kWsFeat);
  int* gcnt    = ws + kWsCnt;
  int* gsorted = ws + kWsSorted;

  const int t = blockIdx.x * 256 + threadIdx.x;
  const int stride = gridDim.x * 256;

  // ---- feature f32 -> permuted bf16 uint4 ----
  for (int i = t; i < kNodes * 8; i += stride) {
    const float* fr = feat + (size_t)(i >> 3) * 64 + (i & 7);
    uint4 p;
    p.x = bf16rne(fr[0])  | (bf16rne(fr[8])  << 16);
    p.y = bf16rne(fr[16]) | (bf16rne(fr[24]) << 16);
    p.z = bf16rne(fr[32]) | (bf16rne(fr[40]) << 16);
    p.w = bf16rne(fr[48]) | (bf16rne(fr[56]) << 16);
    fb16[i] = p;
  }

  // ---- edge scatter: global append into bucket region ----
  for (int e = t; e < kEdges; e += stride) {
    const int s = src[e];
    const int d = dst[e];
    const int bk = d / kBucketNodes;        // magic-multiply const div
    const int dL = d - bk * kBucketNodes;
    const int pos = atomicAdd(&gcnt[bk], 1);
    if (pos < kCap) gsorted[bk * kCap + pos] = s | (dL << 17);
  }
}

// ---------------------------------------------------------------------------
// Kernel 2: one block per bucket (2048 blocks = 2 rounds of 1024 resident),
// 512 threads (8 waves), 4 blocks/CU (~23 KB LDS, wave-capped occupancy).
//  1) dual histogram: deg[dL] (for means) + sh[src>>11] (sort key);
//     edge words read CONTIGUOUSLY from gsorted (no map, no binary search)
//  2) wave-0 shfl exclusive scan of the 64 src-window counters
//  3) rank+scatter into lsrc[] grouped by src-window (ascending src sweep)
//  4) lane-strided sweep gather: 8 lanes/edge, one uint4 (16B) each ->
//     8 fixed-point LDS atomicAdds at {c,8+c,...,56+c}, stride 68.
//  5) accum -> bf16 mean rows via deg[] in hsAll (49 live, 64 allocated)
//  6) MFMA epilogue (waves 0..3): B-frags from global bf16 W table.
// ---------------------------------------------------------------------------
__global__ __launch_bounds__(512, 8) void gcn_aggregate(
    const int*   __restrict__ ws_in,
    const float* __restrict__ b,     // [64]
    float*       __restrict__ out) { // [kNodes][64]
  const uint4* fb16    = (const uint4*)(ws_in + kWsFeat);
  const int* gcnt      = ws_in + kWsCnt;
  const ushort* Wb16g  = (const ushort*)(ws_in + kWsWb);
  const int* gsorted   = ws_in + kWsSorted;

  // lsrc (3KB, phases 1-4) and hsAll (9.2KB, phases 5-6) share storage.
  __shared__ __align__(16) char uShared[64 * 72 * 2];    // 9216 B
  __shared__ __align__(16) int accum[kBucketNodes * kAccStride]; // 13.3 KB
  __shared__ int deg[64];                          // per-dL degree
  __shared__ int sh[64];                           // src-window hist -> cur
  int*    lsrc  = (int*)uShared;
  ushort* hsAll = (ushort*)uShared;

  const int tid = threadIdx.x;
  const int bkt = blockIdx.x;

  if (tid < 64) { deg[tid] = 0; sh[tid] = 0; }
  for (int i = tid; i < kBucketNodes * kAccStride; i += 512) accum[i] = 0;

  int sz = gcnt[bkt];
  if (sz > kCap) sz = kCap;  // never hit for this dataset
  const int ebase = bkt * kCap;

  // ---- 1) dual histogram (degree + src-window); contiguous edge reads ----
  const int j0 = tid, j1 = tid + 512;
  const bool va = j0 < sz, vb = j1 < sz;
  unsigned ea = 0, eb = 0;
  if (va) {
    ea = (unsigned)gsorted[ebase + j0];
    atomicAdd(&deg[ea >> 17], 1);
    atomicAdd(&sh[(ea & 0x1FFFFu) >> 11], 1);
  }
  if (vb) {
    eb = (unsigned)gsorted[ebase + j1];
    atomicAdd(&deg[eb >> 17], 1);
    atomicAdd(&sh[(eb & 0x1FFFFu) >> 11], 1);
  }
  __syncthreads();

  // ---- 2) exclusive scan of 64 src-window counters by wave 0 ----
  if (tid < 64) {
    const int own = sh[tid];
    int s = own;
    #pragma unroll
    for (int off = 1; off < 64; off <<= 1) {
      const int v = __shfl_up(s, off, 64);
      if (tid >= off) s += v;
    }
    sh[tid] = s - own;                   // exclusive; becomes running cursor
  }
  __syncthreads();

  // ---- 3) rank + scatter grouped by src-window (ascending src sweep) ----
  if (va) { const int p = atomicAdd(&sh[(ea & 0x1FFFFu) >> 11], 1); lsrc[p] = (int)ea; }
  if (vb) { const int p = atomicAdd(&sh[(eb & 0x1FFFFu) >> 11], 1); lsrc[p] = (int)eb; }
  __syncthreads();

  // ---- 4) lane-strided sweep gather, fixed-point LDS atomics ----
  const int wave = tid >> 6;
  const int lane = tid & 63;
  const int g = lane >> 3;   // slot within wave (0..7)
  const int c = lane & 7;    // 16B chunk = feats {c,8+c,...,56+c}
  {
    const int slot = wave * 8 + g;           // 0..63
    #pragma unroll 2
    for (int j = slot; j < sz; j += 64) {    // whole block walks in src order
      const unsigned e = (unsigned)lsrc[j];
      const uint4 v = fb16[(size_t)(e & 0x1FFFFu) * 8 + c];
      int* rp = accum + (int)(e >> 17) * kAccStride + c;
      atomicAdd(rp + 0,  (int)(__uint_as_float(v.x << 16)          * kFxScale));
      atomicAdd(rp + 8,  (int)(__uint_as_float(v.x & 0xffff0000u) * kFxScale));
      atomicAdd(rp + 16, (int)(__uint_as_float(v.y << 16)          * kFxScale));
      atomicAdd(rp + 24, (int)(__uint_as_float(v.y & 0xffff0000u) * kFxScale));
      atomicAdd(rp + 32, (int)(__uint_as_float(v.z << 16)          * kFxScale));
      atomicAdd(rp + 40, (int)(__uint_as_float(v.z & 0xffff0000u) * kFxScale));
      atomicAdd(rp + 48, (int)(__uint_as_float(v.w << 16)          * kFxScale));
      atomicAdd(rp + 56, (int)(__uint_as_float(v.w & 0xffff0000u) * kFxScale));
    }
  }
  __syncthreads();

  // ---- 5) accum -> bf16 mean rows via deg[] (over dead lsrc) ----
  {
    const int nd = tid >> 3;          // 0..63; 49 live rows, 8 chunks each
    const int ch = tid & 7;
    if (nd < kBucketNodes) {
      const int dg = deg[nd];
      const float inv = 1.0f / (kFxScale * (float)(dg > 1 ? dg : 1));
      const int* arow = accum + nd * kAccStride + ch * 8;
      const int4 pa = *(const int4*)(arow);
      const int4 pb = *(const int4*)(arow + 4);
      unsigned h0 = bf16rne((float)pa.x * inv);
      unsigned h1 = bf16rne((float)pa.y * inv);
      unsigned h2 = bf16rne((float)pa.z * inv);
      unsigned h3 = bf16rne((float)pa.w * inv);
      unsigned h4 = bf16rne((float)pb.x * inv);
      unsigned h5 = bf16rne((float)pb.y * inv);
      unsigned h6 = bf16rne((float)pb.z * inv);
      unsigned h7 = bf16rne((float)pb.w * inv);
      uint4 pk;
      pk.x = h0 | (h1 << 16);
      pk.y = h2 | (h3 << 16);
      pk.z = h4 | (h5 << 16);
      pk.w = h6 | (h7 << 16);
      *(uint4*)(hsAll + nd * 72 + ch * 8) = pk;
    } else {
      *(uint4*)(hsAll + nd * 72 + ch * 8) = make_uint4(0u, 0u, 0u, 0u);
    }
  }
  __syncthreads();

  // ---- 6) MFMA epilogue (waves 0..3): wave w -> locals [w*16, w*16+16) ----
  if (tid < 256) {
    const int w8   = tid >> 6;        // 0..3
    const int ln   = tid & 63;
    const int quad = ln >> 4;
    const int col  = ln & 15;
    const int n0 = bkt * kBucketNodes;

    const short8 af0 = *reinterpret_cast<const short8*>(
        hsAll + (w8 * 16 + col) * 72 + 0 * 32 + quad * 8);
    const short8 af1 = *reinterpret_cast<const short8*>(
        hsAll + (w8 * 16 + col) * 72 + 1 * 32 + quad * 8);

    #pragma unroll
    for (int ob = 0; ob < 4; ++ob) {
      const short8 bf0 = *reinterpret_cast<const short8*>(
          Wb16g + (ob * 16 + col) * 64 + 0 * 32 + quad * 8);
      const short8 bf1 = *reinterpret_cast<const short8*>(
          Wb16g + (ob * 16 + col) * 64 + 1 * 32 + quad * 8);
      floatx4 acc = {0.f, 0.f, 0.f, 0.f};
      acc = __builtin_amdgcn_mfma_f32_16x16x32_bf16(af0, bf0, acc, 0, 0, 0);
      acc = __builtin_amdgcn_mfma_f32_16x16x32_bf16(af1, bf1, acc, 0, 0, 0);

      const int o = ob * 16 + col;
      const float bo = b[o];
      #pragma unroll
      for (int r = 0; r < 4; ++r) {
        const int local = w8 * 16 + quad * 4 + r;
        const int node = n0 + local;
        if (local < kBucketNodes && node < kNodes) {
          const float v = acc[r] + bo;
          out[(size_t)node * 64 + o] = v > 0.0f ? v : 0.0f;
        }
      }
    }
  }
}

// ---------------------------------------------------------------------------
extern "C" void kernel_launch(void* const* d_in, const int* in_sizes, int n_in,
                              void* d_out, int out_size, void* d_ws, size_t ws_size,
                              hipStream_t stream) {
  const float* feature  = (const float*)d_in[0];
  const int*   edge_src = (const int*)  d_in[1];
  const int*   edge_dst = (const int*)  d_in[2];
  const float* W        = (const float*)d_in[3];
  const float* b        = (const float*)d_in[4];

  float* out = (float*)d_out;
  int*   ws  = (int*)d_ws;

  gcn_prep<<<4, 512, 0, stream>>>(W, ws);
  gcn_build<<<1024, 256, 0, stream>>>(feature, edge_src, edge_dst, ws);
  gcn_aggregate<<<kBuckets, 512, 0, stream>>>(ws, b, out);
}

// Round 7
// 130.452 us; speedup vs baseline: 2.0073x; 2.0073x over previous
//
#include <hip/hip_runtime.h>

// GCN layer: out = relu( segment_mean(feature[edge_src], edge_dst) @ W^T + b )
// N=100000 nodes, E=1200000 edges, 64 feats in/out, all f32.
//
// Round 21: revert to best-measured structure (r15, 128.08us) + one proven
// micro-fix. r20's global-atomic append build was 154us (586 same-address
// atomics per counter serialize at L2; VALUBusy 0.8%) -> LDS per-block
// binning restored. Seven phase-4 variants measured ~equal; r15's
// run-length fixed-point LDS-atomic gather was best -> restored verbatim.
// Single change kept from r19 (independently validated): offsets table
// transposed to offTT[bucket][block], so aggregate phase 0 reads two
// contiguous 1KB rows instead of 2x256 cache lines strided 4KB apart.

typedef __attribute__((ext_vector_type(8))) short short8;   // 8 bf16
typedef __attribute__((ext_vector_type(4))) float floatx4;  // MFMA acc

constexpr int kNodes = 100000;
constexpr int kEdges = 1200000;

constexpr int kBuckets = 1024;
constexpr int kBucketNodes = 98;                    // 1024*98 = 100352 >= N

constexpr int kBinBlocks = 256;
constexpr int kEdgesPerBlock = 4688;                // 256*4688 = 1200128 >= E
constexpr int kEPT = (kEdgesPerBlock + 1023) / 1024; // 5

constexpr int kCap = 2048;        // max edges/bucket (mean 1172, ~26 sigma)
constexpr float kFxScale = 262144.0f;   // 2^18 fixed-point scale
constexpr int kAccStride = 68;    // adds at {c,16+c,32+c,48+c}

// Workspace layout (int elements). Total ~18.7 MB.
constexpr int kWsFeat   = 0;                        // uint2[1600000] (12.8MB)
constexpr int kWsOff    = 3200000;                  // int[1025][256] transposed
constexpr int kWsBinned = kWsOff + (kBuckets + 1) * kBinBlocks;  // int[256*4688]

__device__ __forceinline__ unsigned bf16rne(float f) {
  unsigned u = __float_as_uint(f);
  return (u + 0x7fffu + ((u >> 16) & 1u)) >> 16;  // round-to-nearest-even
}

// ---------------------------------------------------------------------------
// Kernel 1: feature conversion + single-pass deterministic bucket binning.
// Conversion: permuted bf16 rows — halfword k of a row stores
// feat[(k&3)*16 + (k>>2)], so 8B chunk c = feats {c,16+c,32+c,48+c}.
// Binning: <=4688 edges cached in registers -> LDS bucket hist (bucket=dst/98)
// -> two-level shfl exclusive scan (1024 wide) -> offTT (transposed) ->
// rank+scatter packed words (src | dL<<17, dL<98).
// ---------------------------------------------------------------------------
__global__ __launch_bounds__(1024) void gcn_build(
    const float* __restrict__ feat,
    const int* __restrict__ src, const int* __restrict__ dst,
    int* __restrict__ ws) {
  uint2* fb16 = (uint2*)(ws + kWsFeat);
  int* offTT  = ws + kWsOff;
  int* binned = ws + kWsBinned;

  __shared__ int lhist[kBuckets];
  __shared__ int lcur[kBuckets];
  __shared__ int wsum[16];

  const int tid = threadIdx.x;
  lhist[tid] = 0;
  __syncthreads();

  // ---- edge slice load + bucket histogram ----
  const int e0 = blockIdx.x * kEdgesPerBlock;
  const int cnt = min(kEdgesPerBlock, kEdges - e0);   // last block: 4560
  int es[kEPT], ebk[kEPT], edl[kEPT];
  #pragma unroll
  for (int k = 0; k < kEPT; ++k) {
    const int j = tid + k * 1024;
    if (j < cnt) {
      es[k] = src[e0 + j];
      const int d = dst[e0 + j];
      const int bk = d / kBucketNodes;      // magic-multiply const div
      ebk[k] = bk;
      edl[k] = d - bk * kBucketNodes;
      atomicAdd(&lhist[bk], 1);
    }
  }

  // ---- feature f32 -> permuted bf16 (independent; overlaps hist latency) ----
  const int t = blockIdx.x * 1024 + tid;
  for (int i = t; i < kNodes * 16; i += kBinBlocks * 1024) {
    const float* fr = feat + (size_t)(i >> 4) * 64 + (i & 15);
    uint2 p;
    p.x = bf16rne(fr[0])  | (bf16rne(fr[16]) << 16);
    p.y = bf16rne(fr[32]) | (bf16rne(fr[48]) << 16);
    fb16[i] = p;
  }
  __syncthreads();

  // ---- two-level shfl exclusive scan over 1024 counts ----
  const int own = lhist[tid];
  const int wv = tid >> 6, ln = tid & 63;
  int sc = own;
  #pragma unroll
  for (int off = 1; off < 64; off <<= 1) {
    const int v = __shfl_up(sc, off, 64);
    if (ln >= off) sc += v;
  }
  if (ln == 63) wsum[wv] = sc;            // wave totals
  __syncthreads();
  if (tid < 64) {
    int tw = (tid < 16) ? wsum[tid] : 0;
    #pragma unroll
    for (int off = 1; off < 16; off <<= 1) {
      const int v = __shfl_up(tw, off, 64);
      if (tid >= off) tw += v;
    }
    if (tid < 16) wsum[tid] = tw;          // inclusive wave prefix
  }
  __syncthreads();
  const int excl = sc - own + (wv ? wsum[wv - 1] : 0);
  lcur[tid] = excl;
  offTT[tid * kBinBlocks + blockIdx.x] = excl;   // transposed (L2 combines)
  if (tid == 0) offTT[kBuckets * kBinBlocks + blockIdx.x] = cnt;
  __syncthreads();

  // ---- rank + scatter into this block's bucket-grouped region ----
  int* myBin = binned + blockIdx.x * kEdgesPerBlock;
  #pragma unroll
  for (int k = 0; k < kEPT; ++k) {
    const int j = tid + k * 1024;
    if (j < cnt) {
      const int pos = atomicAdd(&lcur[ebk[k]], 1);  // LDS int atomic
      myBin[pos] = es[k] | (edl[k] << 17);
    }
  }
}

// ---------------------------------------------------------------------------
// Kernel 2: one block per bucket (1024 blocks = 2 full occupancy rounds),
// 1024 threads (16 waves), 2 blocks/CU.
//  0) segment map over the 256 block regions (two contiguous offTT rows)
//  1) local-dst histogram (edge words cached in registers, <=2/thread)
//  2) wave-0 shfl scan of 128 counters (98 live) -> lofs[]
//  3) rank+scatter packed words into lsrc[] (CSR sorted by dL)
//  4) edge-parallel gather, perfect balance: slot s (of 64) owns edges
//     [sz*s/64, sz*(s+1)/64); runs of equal dL accumulated in 4 float regs,
//     fixed-point ds_add flush at run boundaries (deterministic: int adds
//     commute).
//  5) accum -> bf16 mean rows in hsAll (98 rows live, 112 allocated)
//  6) MFMA epilogue (waves 0..6): 16-node tiles, guard local<98.
// ---------------------------------------------------------------------------
__global__ __launch_bounds__(1024, 8) void gcn_aggregate(
    const int*   __restrict__ ws_in,
    const float* __restrict__ W,     // [64][64] row-major W[o][d]
    const float* __restrict__ b,     // [64]
    float*       __restrict__ out) { // [kNodes][64]
  const uint2* fb16 = (const uint2*)(ws_in + kWsFeat);
  const int* offTT  = ws_in + kWsOff;
  const int* binned = ws_in + kWsBinned;

  // lsrc (8KB, phases 1-4) and hsAll (16.1KB, phases 5-6) share storage.
  __shared__ __align__(16) char uShared[112 * 72 * 2];   // 16128 B
  __shared__ int    accum[kBucketNodes * kAccStride];    // 26.7 KB fixed-point
  __shared__ int    lofs[129];
  __shared__ int    lcur[128];
  __shared__ int    runL[kBinBlocks + 1];
  __shared__ int    runG[kBinBlocks];
  __shared__ int    ssm[kBinBlocks];
  __shared__ ushort Wb16[64 * 64];                 // 8 KB, natural W[o][d]
  __shared__ float  bsh[64];
  int*    lsrc  = (int*)uShared;
  ushort* hsAll = (ushort*)uShared;

  const int tid = threadIdx.x;
  const int bkt = blockIdx.x;

  if (tid < 128) lcur[tid] = 0;
  for (int i = tid; i < 4096; i += 1024) Wb16[i] = (ushort)bf16rne(W[i]);
  if (tid < 64) bsh[tid] = b[tid];
  for (int i = tid; i < kBucketNodes * kAccStride; i += 1024) accum[i] = 0;

  // ---- 0) segment map over the 256 block regions ----
  int len = 0;
  if (tid < kBinBlocks) {
    const int o0 = offTT[bkt * kBinBlocks + tid];         // contiguous row
    const int o1 = offTT[(bkt + 1) * kBinBlocks + tid];   // next row
    len = o1 - o0;
    runG[tid] = tid * kEdgesPerBlock + o0;
    ssm[tid] = len;
  }
  __syncthreads();
  if (tid < 64) {                        // wave-0 shfl scan, 4 elems/lane
    const int base = tid * 4;
    const int v0 = ssm[base], v1 = ssm[base + 1];
    const int v2 = ssm[base + 2], v3 = ssm[base + 3];
    const int p1 = v0 + v1, p2 = p1 + v2, tot = p2 + v3;
    int sc = tot;
    #pragma unroll
    for (int off = 1; off < 64; off <<= 1) {
      const int v = __shfl_up(sc, off, 64);
      if (tid >= off) sc += v;
    }
    const int ex = sc - tot;             // exclusive prefix of lane total
    runL[base]     = ex;
    runL[base + 1] = ex + v0;
    runL[base + 2] = ex + p1;
    runL[base + 3] = ex + p2;
    if (tid == 63) runL[kBinBlocks] = sc;
  }
  __syncthreads();

  int sz = runL[kBinBlocks];
  if (sz > kCap) sz = kCap;  // never hit for this dataset

  // j -> global binned index via 8-step binary search over runL
  auto mapRead = [&](int j) -> unsigned {
    int lo = 0, hi = kBinBlocks;
    #pragma unroll
    for (int it = 0; it < 8; ++it) {
      const int mid = (lo + hi) >> 1;
      if (runL[mid] <= j) lo = mid; else hi = mid;
    }
    return (unsigned)binned[runG[lo] + (j - runL[lo])];
  };

  // ---- 1) local-dst histogram; cache edge words in registers ----
  const int j0 = tid, j1 = tid + 1024;
  const bool va = j0 < sz, vb = j1 < sz;
  unsigned ea = 0, eb = 0;
  if (va) { ea = mapRead(j0); atomicAdd(&lcur[ea >> 17], 1); }
  if (vb) { eb = mapRead(j1); atomicAdd(&lcur[eb >> 17], 1); }
  __syncthreads();

  // ---- 2) exclusive scan of 128 counters by wave 0 (98 live) ----
  if (tid < 64) {
    const int a  = lcur[tid * 2];
    const int b2 = lcur[tid * 2 + 1];
    int s = a + b2;
    #pragma unroll
    for (int off = 1; off < 64; off <<= 1) {
      const int v = __shfl_up(s, off, 64);
      if (tid >= off) s += v;
    }
    const int ex1 = s - b2;
    const int ex0 = ex1 - a;
    lofs[tid * 2]     = ex0;
    lofs[tid * 2 + 1] = ex1;
    lcur[tid * 2]     = ex0;
    lcur[tid * 2 + 1] = ex1;
    if (tid == 63) lofs[128] = s;
  }
  __syncthreads();

  // ---- 3) rank + scatter into bucket-local CSR (sorted by dL) ----
  if (va) { const int p = atomicAdd(&lcur[ea >> 17], 1); lsrc[p] = (int)ea; }
  if (vb) { const int p = atomicAdd(&lcur[eb >> 17], 1); lsrc[p] = (int)eb; }
  __syncthreads();

  // ---- 4) balanced edge gather with run-length accumulation ----
  const int wave = tid >> 6;
  const int lane = tid & 63;
  const int g = lane >> 4;   // slot within wave
  const int c = lane & 15;   // 8B chunk = feats {c,16+c,32+c,48+c}
  {
    const int slot = wave * 4 + g;           // 0..63
    const int jb = (sz * slot) >> 6;
    const int je = (sz * (slot + 1)) >> 6;
    int curDL = -1;
    float a0 = 0.f, a1 = 0.f, a2 = 0.f, a3 = 0.f;
    for (int j = jb; j < je; ++j) {
      const unsigned e = (unsigned)lsrc[j];   // uniform within 16-lane group
      const int dL = (int)(e >> 17);
      if (dL != curDL) {                      // diverges only across 4 groups
        if (curDL >= 0) {
          int* row = accum + curDL * kAccStride + c;
          atomicAdd(row + 0,  (int)(a0 * kFxScale));
          atomicAdd(row + 16, (int)(a1 * kFxScale));
          atomicAdd(row + 32, (int)(a2 * kFxScale));
          atomicAdd(row + 48, (int)(a3 * kFxScale));
        }
        curDL = dL;
        a0 = a1 = a2 = a3 = 0.f;
      }
      const uint2 v = fb16[(size_t)(e & 0x1FFFF) * 16 + c];
      a0 += __uint_as_float(v.x << 16);
      a1 += __uint_as_float(v.x & 0xffff0000u);
      a2 += __uint_as_float(v.y << 16);
      a3 += __uint_as_float(v.y & 0xffff0000u);
    }
    if (curDL >= 0) {
      int* row = accum + curDL * kAccStride + c;
      atomicAdd(row + 0,  (int)(a0 * kFxScale));
      atomicAdd(row + 16, (int)(a1 * kFxScale));
      atomicAdd(row + 32, (int)(a2 * kFxScale));
      atomicAdd(row + 48, (int)(a3 * kFxScale));
    }
  }
  __syncthreads();

  // ---- 5) accum -> bf16 mean rows in hsAll (over dead lsrc) ----
  {
    const int nd = tid >> 3;          // 0..127; 98 live rows, 8 chunks each
    const int ch = tid & 7;
    if (nd < kBucketNodes) {
      const int dg = lofs[nd + 1] - lofs[nd];
      const float inv = 1.0f / (kFxScale * (float)(dg > 1 ? dg : 1));
      const int* arow = accum + nd * kAccStride + ch * 8;
      unsigned h[8];
      #pragma unroll
      for (int q = 0; q < 8; ++q) h[q] = bf16rne((float)arow[q] * inv);
      uint4 pk;
      pk.x = h[0] | (h[1] << 16);
      pk.y = h[2] | (h[3] << 16);
      pk.z = h[4] | (h[5] << 16);
      pk.w = h[6] | (h[7] << 16);
      *(uint4*)(hsAll + nd * 72 + ch * 8) = pk;
    } else {
      if (nd < 112) *(uint4*)(hsAll + nd * 72 + ch * 8) =
          make_uint4(0u, 0u, 0u, 0u);
    }
  }
  __syncthreads();

  // ---- 6) MFMA epilogue (waves 0..6): wave w -> locals [w*16, w*16+16) ----
  if (tid < 448) {
    const int w8   = tid >> 6;        // 0..6
    const int ln   = tid & 63;
    const int quad = ln >> 4;
    const int col  = ln & 15;
    const int n0 = bkt * kBucketNodes;

    const short8 af0 = *reinterpret_cast<const short8*>(
        hsAll + (w8 * 16 + col) * 72 + 0 * 32 + quad * 8);
    const short8 af1 = *reinterpret_cast<const short8*>(
        hsAll + (w8 * 16 + col) * 72 + 1 * 32 + quad * 8);

    #pragma unroll
    for (int ob = 0; ob < 4; ++ob) {
      const short8 bf0 = *reinterpret_cast<const short8*>(
          Wb16 + (ob * 16 + col) * 64 + 0 * 32 + quad * 8);
      const short8 bf1 = *reinterpret_cast<const short8*>(
          Wb16 + (ob * 16 + col) * 64 + 1 * 32 + quad * 8);
      floatx4 acc = {0.f, 0.f, 0.f, 0.f};
      acc = __builtin_amdgcn_mfma_f32_16x16x32_bf16(af0, bf0, acc, 0, 0, 0);
      acc = __builtin_amdgcn_mfma_f32_16x16x32_bf16(af1, bf1, acc, 0, 0, 0);

      const int o = ob * 16 + col;
      const float bo = bsh[o];
      #pragma unroll
      for (int r = 0; r < 4; ++r) {
        const int local = w8 * 16 + quad * 4 + r;
        const int node = n0 + local;
        if (local < kBucketNodes && node < kNodes) {
          const float v = acc[r] + bo;
          out[(size_t)node * 64 + o] = v > 0.0f ? v : 0.0f;
        }
      }
    }
  }
}

// ---------------------------------------------------------------------------
extern "C" void kernel_launch(void* const* d_in, const int* in_sizes, int n_in,
                              void* d_out, int out_size, void* d_ws, size_t ws_size,
                              hipStream_t stream) {
  const float* feature  = (const float*)d_in[0];
  const int*   edge_src = (const int*)  d_in[1];
  const int*   edge_dst = (const int*)  d_in[2];
  const float* W        = (const float*)d_in[3];
  const float* b        = (const float*)d_in[4];

  float* out = (float*)d_out;
  int*   ws  = (int*)d_ws;

  gcn_build<<<kBinBlocks, 1024, 0, stream>>>(feature, edge_src, edge_dst, ws);
  gcn_aggregate<<<kBuckets, 1024, 0, stream>>>(ws, W, b, out);
}

// Round 8
// 128.050 us; speedup vs baseline: 2.0450x; 1.0188x over previous
//
#include <hip/hip_runtime.h>

// GCN layer: out = relu( segment_mean(feature[edge_src], edge_dst) @ W^T + b )
// N=100000 nodes, E=1200000 edges, 64 feats in/out, all f32.
//
// Round 22: r15 frame (best measured, 128.08us) + ONE variable: src-sweep
// gather. offTT transpose reverted (r21: build line-scatter cost >= phase-0
// saving). Aggregate keeps r15's phases 0-1 (segment map + mapRead), but the
// in-bucket counting sort now keys on SRC-WINDOW (src>>10; 98 windows of
// 1024 nodes = 128KB fb16 each) instead of dst-local; degrees for the mean
// come from an exact deg[dL] histogram. Phase 4 walks the src-sorted list
// lane-strided (j=slot; j+=64): all 64 slots + all 512 resident blocks sweep
// fb16 low->high together, so degree-12 row re-reads hit L2 instead of
// spilling to L3/HBM (r16 PMC: FETCH 78MB vs 12.8MB table, ~30% L2 hit).
// Per-edge fixed-point LDS atomics: int adds commute -> bit-stable output.

typedef __attribute__((ext_vector_type(8))) short short8;   // 8 bf16
typedef __attribute__((ext_vector_type(4))) float floatx4;  // MFMA acc

constexpr int kNodes = 100000;
constexpr int kEdges = 1200000;

constexpr int kBuckets = 1024;
constexpr int kBucketNodes = 98;                    // 1024*98 = 100352 >= N

constexpr int kBinBlocks = 256;
constexpr int kEdgesPerBlock = 4688;                // 256*4688 = 1200128 >= E
constexpr int kEPT = (kEdgesPerBlock + 1023) / 1024; // 5

constexpr int kCap = 2048;        // max edges/bucket (mean 1172, ~26 sigma)
constexpr float kFxScale = 262144.0f;   // 2^18 fixed-point scale
constexpr int kAccStride = 68;    // adds at {c,16+c,32+c,48+c}

// Workspace layout (int elements). Total ~18.7 MB.
constexpr int kWsFeat   = 0;                        // uint2[1600000] (12.8MB)
constexpr int kWsOff    = 3200000;                  // int[256][1025] row-major
constexpr int kWsBinned = kWsOff + kBinBlocks * (kBuckets + 1);  // int[256*4688]

__device__ __forceinline__ unsigned bf16rne(float f) {
  unsigned u = __float_as_uint(f);
  return (u + 0x7fffu + ((u >> 16) & 1u)) >> 16;  // round-to-nearest-even
}

// ---------------------------------------------------------------------------
// Kernel 1: feature conversion + single-pass deterministic bucket binning.
// (r15 verbatim: 256 blocks, register edge cache, two-level shfl scan,
//  row-major offT with coalesced writes)
// ---------------------------------------------------------------------------
__global__ __launch_bounds__(1024) void gcn_build(
    const float* __restrict__ feat,
    const int* __restrict__ src, const int* __restrict__ dst,
    int* __restrict__ ws) {
  uint2* fb16 = (uint2*)(ws + kWsFeat);
  int* offT   = ws + kWsOff;
  int* binned = ws + kWsBinned;

  __shared__ int lhist[kBuckets];
  __shared__ int lcur[kBuckets];
  __shared__ int wsum[16];

  const int tid = threadIdx.x;
  lhist[tid] = 0;
  __syncthreads();

  // ---- edge slice load + bucket histogram ----
  const int e0 = blockIdx.x * kEdgesPerBlock;
  const int cnt = min(kEdgesPerBlock, kEdges - e0);   // last block: 4560
  int es[kEPT], ebk[kEPT], edl[kEPT];
  #pragma unroll
  for (int k = 0; k < kEPT; ++k) {
    const int j = tid + k * 1024;
    if (j < cnt) {
      es[k] = src[e0 + j];
      const int d = dst[e0 + j];
      const int bk = d / kBucketNodes;      // magic-multiply const div
      ebk[k] = bk;
      edl[k] = d - bk * kBucketNodes;
      atomicAdd(&lhist[bk], 1);
    }
  }

  // ---- feature f32 -> permuted bf16 (independent; overlaps hist latency) ----
  const int t = blockIdx.x * 1024 + tid;
  for (int i = t; i < kNodes * 16; i += kBinBlocks * 1024) {
    const float* fr = feat + (size_t)(i >> 4) * 64 + (i & 15);
    uint2 p;
    p.x = bf16rne(fr[0])  | (bf16rne(fr[16]) << 16);
    p.y = bf16rne(fr[32]) | (bf16rne(fr[48]) << 16);
    fb16[i] = p;
  }
  __syncthreads();

  // ---- two-level shfl exclusive scan over 1024 counts ----
  const int own = lhist[tid];
  const int wv = tid >> 6, ln = tid & 63;
  int sc = own;
  #pragma unroll
  for (int off = 1; off < 64; off <<= 1) {
    const int v = __shfl_up(sc, off, 64);
    if (ln >= off) sc += v;
  }
  if (ln == 63) wsum[wv] = sc;            // wave totals
  __syncthreads();
  if (tid < 64) {
    int tw = (tid < 16) ? wsum[tid] : 0;
    #pragma unroll
    for (int off = 1; off < 16; off <<= 1) {
      const int v = __shfl_up(tw, off, 64);
      if (tid >= off) tw += v;
    }
    if (tid < 16) wsum[tid] = tw;          // inclusive wave prefix
  }
  __syncthreads();
  const int excl = sc - own + (wv ? wsum[wv - 1] : 0);
  lcur[tid] = excl;
  offT[blockIdx.x * (kBuckets + 1) + tid] = excl;          // coalesced
  if (tid == 0) offT[blockIdx.x * (kBuckets + 1) + kBuckets] = cnt;
  __syncthreads();

  // ---- rank + scatter into this block's bucket-grouped region ----
  int* myBin = binned + blockIdx.x * kEdgesPerBlock;
  #pragma unroll
  for (int k = 0; k < kEPT; ++k) {
    const int j = tid + k * 1024;
    if (j < cnt) {
      const int pos = atomicAdd(&lcur[ebk[k]], 1);  // LDS int atomic
      myBin[pos] = es[k] | (edl[k] << 17);
    }
  }
}

// ---------------------------------------------------------------------------
// Kernel 2: one block per bucket (1024 blocks = 2 full occupancy rounds),
// 1024 threads (16 waves), 2 blocks/CU.
//  0) segment map over the 256 block regions (r15 verbatim)
//  1) dual histogram: deg[dL] (exact, for means) + wcur[src>>10] (sort key);
//     edge words via mapRead, cached in registers (<=2/thread)
//  2) wave-0 pairwise shfl scan of 128 window counters (98 live)
//  3) rank+scatter into lsrc[] grouped by src-window (ascending src)
//  4) lane-strided sweep gather: slot s takes j=s,s+64,...; 16 lanes/edge,
//     uint2 each -> 4 fixed-point LDS atomicAdds at {c,16+c,32+c,48+c}.
//     Whole machine sweeps fb16 in src order => L2-resident re-reads.
//  5) accum -> bf16 mean rows via deg[] in hsAll (98 live, 112 allocated)
//  6) MFMA epilogue (waves 0..6): 16-node tiles, guard local<98.
// ---------------------------------------------------------------------------
__global__ __launch_bounds__(1024, 8) void gcn_aggregate(
    const int*   __restrict__ ws_in,
    const float* __restrict__ W,     // [64][64] row-major W[o][d]
    const float* __restrict__ b,     // [64]
    float*       __restrict__ out) { // [kNodes][64]
  const uint2* fb16 = (const uint2*)(ws_in + kWsFeat);
  const int* offT   = ws_in + kWsOff;
  const int* binned = ws_in + kWsBinned;

  // lsrc (8KB, phases 1-4) and hsAll (16.1KB, phases 5-6) share storage.
  __shared__ __align__(16) char uShared[112 * 72 * 2];   // 16128 B
  __shared__ int    accum[kBucketNodes * kAccStride];    // 26.7 KB fixed-point
  __shared__ int    deg[128];                            // per-dL degree
  __shared__ int    wcur[128];                           // window hist -> cur
  __shared__ int    runL[kBinBlocks + 1];
  __shared__ int    runG[kBinBlocks];
  __shared__ int    ssm[kBinBlocks];
  __shared__ ushort Wb16[64 * 64];                 // 8 KB, natural W[o][d]
  __shared__ float  bsh[64];
  int*    lsrc  = (int*)uShared;
  ushort* hsAll = (ushort*)uShared;

  const int tid = threadIdx.x;
  const int bkt = blockIdx.x;

  if (tid < 128) { deg[tid] = 0; wcur[tid] = 0; }
  for (int i = tid; i < 4096; i += 1024) Wb16[i] = (ushort)bf16rne(W[i]);
  if (tid < 64) bsh[tid] = b[tid];
  for (int i = tid; i < kBucketNodes * kAccStride; i += 1024) accum[i] = 0;

  // ---- 0) segment map over the 256 block regions ----
  int len = 0;
  if (tid < kBinBlocks) {
    const int o0 = offT[tid * (kBuckets + 1) + bkt];
    const int o1 = offT[tid * (kBuckets + 1) + bkt + 1];
    len = o1 - o0;
    runG[tid] = tid * kEdgesPerBlock + o0;
    ssm[tid] = len;
  }
  __syncthreads();
  if (tid < 64) {                        // wave-0 shfl scan, 4 elems/lane
    const int base = tid * 4;
    const int v0 = ssm[base], v1 = ssm[base + 1];
    const int v2 = ssm[base + 2], v3 = ssm[base + 3];
    const int p1 = v0 + v1, p2 = p1 + v2, tot = p2 + v3;
    int sc = tot;
    #pragma unroll
    for (int off = 1; off < 64; off <<= 1) {
      const int v = __shfl_up(sc, off, 64);
      if (tid >= off) sc += v;
    }
    const int ex = sc - tot;             // exclusive prefix of lane total
    runL[base]     = ex;
    runL[base + 1] = ex + v0;
    runL[base + 2] = ex + p1;
    runL[base + 3] = ex + p2;
    if (tid == 63) runL[kBinBlocks] = sc;
  }
  __syncthreads();

  int sz = runL[kBinBlocks];
  if (sz > kCap) sz = kCap;  // never hit for this dataset

  // j -> global binned index via 8-step binary search over runL
  auto mapRead = [&](int j) -> unsigned {
    int lo = 0, hi = kBinBlocks;
    #pragma unroll
    for (int it = 0; it < 8; ++it) {
      const int mid = (lo + hi) >> 1;
      if (runL[mid] <= j) lo = mid; else hi = mid;
    }
    return (unsigned)binned[runG[lo] + (j - runL[lo])];
  };

  // ---- 1) dual histogram (degree + src-window); cache edge words ----
  const int j0 = tid, j1 = tid + 1024;
  const bool va = j0 < sz, vb = j1 < sz;
  unsigned ea = 0, eb = 0;
  if (va) {
    ea = mapRead(j0);
    atomicAdd(&deg[ea >> 17], 1);
    atomicAdd(&wcur[(ea & 0x1FFFFu) >> 10], 1);
  }
  if (vb) {
    eb = mapRead(j1);
    atomicAdd(&deg[eb >> 17], 1);
    atomicAdd(&wcur[(eb & 0x1FFFFu) >> 10], 1);
  }
  __syncthreads();

  // ---- 2) exclusive scan of 128 window counters by wave 0 (98 live) ----
  if (tid < 64) {
    const int a  = wcur[tid * 2];
    const int b2 = wcur[tid * 2 + 1];
    int s = a + b2;
    #pragma unroll
    for (int off = 1; off < 64; off <<= 1) {
      const int v = __shfl_up(s, off, 64);
      if (tid >= off) s += v;
    }
    const int ex1 = s - b2;
    const int ex0 = ex1 - a;
    wcur[tid * 2]     = ex0;
    wcur[tid * 2 + 1] = ex1;
  }
  __syncthreads();

  // ---- 3) rank + scatter grouped by src-window (ascending src sweep) ----
  if (va) { const int p = atomicAdd(&wcur[(ea & 0x1FFFFu) >> 10], 1); lsrc[p] = (int)ea; }
  if (vb) { const int p = atomicAdd(&wcur[(eb & 0x1FFFFu) >> 10], 1); lsrc[p] = (int)eb; }
  __syncthreads();

  // ---- 4) lane-strided sweep gather, fixed-point LDS atomics ----
  const int wave = tid >> 6;
  const int lane = tid & 63;
  const int g = lane >> 4;   // slot within wave
  const int c = lane & 15;   // 8B chunk = feats {c,16+c,32+c,48+c}
  {
    const int slot = wave * 4 + g;           // 0..63
    #pragma unroll 2
    for (int j = slot; j < sz; j += 64) {    // whole block walks in src order
      const unsigned e = (unsigned)lsrc[j];  // uniform within 16-lane group
      const uint2 v = fb16[(size_t)(e & 0x1FFFFu) * 16 + c];
      int* rp = accum + (int)(e >> 17) * kAccStride + c;
      atomicAdd(rp + 0,  (int)(__uint_as_float(v.x << 16)          * kFxScale));
      atomicAdd(rp + 16, (int)(__uint_as_float(v.x & 0xffff0000u) * kFxScale));
      atomicAdd(rp + 32, (int)(__uint_as_float(v.y << 16)          * kFxScale));
      atomicAdd(rp + 48, (int)(__uint_as_float(v.y & 0xffff0000u) * kFxScale));
    }
  }
  __syncthreads();

  // ---- 5) accum -> bf16 mean rows via deg[] (over dead lsrc) ----
  {
    const int nd = tid >> 3;          // 0..127; 98 live rows, 8 chunks each
    const int ch = tid & 7;
    if (nd < kBucketNodes) {
      const int dg = deg[nd];
      const float inv = 1.0f / (kFxScale * (float)(dg > 1 ? dg : 1));
      const int* arow = accum + nd * kAccStride + ch * 8;
      unsigned h[8];
      #pragma unroll
      for (int q = 0; q < 8; ++q) h[q] = bf16rne((float)arow[q] * inv);
      uint4 pk;
      pk.x = h[0] | (h[1] << 16);
      pk.y = h[2] | (h[3] << 16);
      pk.z = h[4] | (h[5] << 16);
      pk.w = h[6] | (h[7] << 16);
      *(uint4*)(hsAll + nd * 72 + ch * 8) = pk;
    } else {
      if (nd < 112) *(uint4*)(hsAll + nd * 72 + ch * 8) =
          make_uint4(0u, 0u, 0u, 0u);
    }
  }
  __syncthreads();

  // ---- 6) MFMA epilogue (waves 0..6): wave w -> locals [w*16, w*16+16) ----
  if (tid < 448) {
    const int w8   = tid >> 6;        // 0..6
    const int ln   = tid & 63;
    const int quad = ln >> 4;
    const int col  = ln & 15;
    const int n0 = bkt * kBucketNodes;

    const short8 af0 = *reinterpret_cast<const short8*>(
        hsAll + (w8 * 16 + col) * 72 + 0 * 32 + quad * 8);
    const short8 af1 = *reinterpret_cast<const short8*>(
        hsAll + (w8 * 16 + col) * 72 + 1 * 32 + quad * 8);

    #pragma unroll
    for (int ob = 0; ob < 4; ++ob) {
      const short8 bf0 = *reinterpret_cast<const short8*>(
          Wb16 + (ob * 16 + col) * 64 + 0 * 32 + quad * 8);
      const short8 bf1 = *reinterpret_cast<const short8*>(
          Wb16 + (ob * 16 + col) * 64 + 1 * 32 + quad * 8);
      floatx4 acc = {0.f, 0.f, 0.f, 0.f};
      acc = __builtin_amdgcn_mfma_f32_16x16x32_bf16(af0, bf0, acc, 0, 0, 0);
      acc = __builtin_amdgcn_mfma_f32_16x16x32_bf16(af1, bf1, acc, 0, 0, 0);

      const int o = ob * 16 + col;
      const float bo = bsh[o];
      #pragma unroll
      for (int r = 0; r < 4; ++r) {
        const int local = w8 * 16 + quad * 4 + r;
        const int node = n0 + local;
        if (local < kBucketNodes && node < kNodes) {
          const float v = acc[r] + bo;
          out[(size_t)node * 64 + o] = v > 0.0f ? v : 0.0f;
        }
      }
    }
  }
}

// ---------------------------------------------------------------------------
extern "C" void kernel_launch(void* const* d_in, const int* in_sizes, int n_in,
                              void* d_out, int out_size, void* d_ws, size_t ws_size,
                              hipStream_t stream) {
  const float* feature  = (const float*)d_in[0];
  const int*   edge_src = (const int*)  d_in[1];
  const int*   edge_dst = (const int*)  d_in[2];
  const float* W        = (const float*)d_in[3];
  const float* b        = (const float*)d_in[4];

  float* out = (float*)d_out;
  int*   ws  = (int*)d_ws;

  gcn_build<<<kBinBlocks, 1024, 0, stream>>>(feature, edge_src, edge_dst, ws);
  gcn_aggregate<<<kBuckets, 1024, 0, stream>>>(ws, W, b, out);
}

// Round 9
// 126.126 us; speedup vs baseline: 2.0762x; 1.0153x over previous
//
#include <hip/hip_runtime.h>

// GCN layer: out = relu( segment_mean(feature[edge_src], edge_dst) @ W^T + b )
// N=100000 nodes, E=1200000 edges, 64 feats in/out, all f32.
//
// Round 23: r22 frame (tied best measured, 128.05us) + ONE variable:
// 4-deep software-pipelined gather in aggregate phase 4. The loop was
// {lsrc ds_read (~120cy) -> dependent 8B gather (~200-900cy) -> 4 ds_adds}
// x ~18 iterations with unroll 2 (2 loads in flight). Now: batch of 4 -
// read e[j],e[j+64],e[j+128],e[j+192] (independent LDS reads), issue all
// 4 independent fb16 gathers, then 16 fixed-point LDS atomics. 2x MLP in
// the dominant ~20us phase. Determinism unchanged (int adds commute).

typedef __attribute__((ext_vector_type(8))) short short8;   // 8 bf16
typedef __attribute__((ext_vector_type(4))) float floatx4;  // MFMA acc

constexpr int kNodes = 100000;
constexpr int kEdges = 1200000;

constexpr int kBuckets = 1024;
constexpr int kBucketNodes = 98;                    // 1024*98 = 100352 >= N

constexpr int kBinBlocks = 256;
constexpr int kEdgesPerBlock = 4688;                // 256*4688 = 1200128 >= E
constexpr int kEPT = (kEdgesPerBlock + 1023) / 1024; // 5

constexpr int kCap = 2048;        // max edges/bucket (mean 1172, ~26 sigma)
constexpr float kFxScale = 262144.0f;   // 2^18 fixed-point scale
constexpr int kAccStride = 68;    // adds at {c,16+c,32+c,48+c}

// Workspace layout (int elements). Total ~18.7 MB.
constexpr int kWsFeat   = 0;                        // uint2[1600000] (12.8MB)
constexpr int kWsOff    = 3200000;                  // int[256][1025] row-major
constexpr int kWsBinned = kWsOff + kBinBlocks * (kBuckets + 1);  // int[256*4688]

__device__ __forceinline__ unsigned bf16rne(float f) {
  unsigned u = __float_as_uint(f);
  return (u + 0x7fffu + ((u >> 16) & 1u)) >> 16;  // round-to-nearest-even
}

// ---------------------------------------------------------------------------
// Kernel 1: feature conversion + single-pass deterministic bucket binning.
// (r15/r22 verbatim)
// ---------------------------------------------------------------------------
__global__ __launch_bounds__(1024) void gcn_build(
    const float* __restrict__ feat,
    const int* __restrict__ src, const int* __restrict__ dst,
    int* __restrict__ ws) {
  uint2* fb16 = (uint2*)(ws + kWsFeat);
  int* offT   = ws + kWsOff;
  int* binned = ws + kWsBinned;

  __shared__ int lhist[kBuckets];
  __shared__ int lcur[kBuckets];
  __shared__ int wsum[16];

  const int tid = threadIdx.x;
  lhist[tid] = 0;
  __syncthreads();

  // ---- edge slice load + bucket histogram ----
  const int e0 = blockIdx.x * kEdgesPerBlock;
  const int cnt = min(kEdgesPerBlock, kEdges - e0);   // last block: 4560
  int es[kEPT], ebk[kEPT], edl[kEPT];
  #pragma unroll
  for (int k = 0; k < kEPT; ++k) {
    const int j = tid + k * 1024;
    if (j < cnt) {
      es[k] = src[e0 + j];
      const int d = dst[e0 + j];
      const int bk = d / kBucketNodes;      // magic-multiply const div
      ebk[k] = bk;
      edl[k] = d - bk * kBucketNodes;
      atomicAdd(&lhist[bk], 1);
    }
  }

  // ---- feature f32 -> permuted bf16 (independent; overlaps hist latency) ----
  const int t = blockIdx.x * 1024 + tid;
  for (int i = t; i < kNodes * 16; i += kBinBlocks * 1024) {
    const float* fr = feat + (size_t)(i >> 4) * 64 + (i & 15);
    uint2 p;
    p.x = bf16rne(fr[0])  | (bf16rne(fr[16]) << 16);
    p.y = bf16rne(fr[32]) | (bf16rne(fr[48]) << 16);
    fb16[i] = p;
  }
  __syncthreads();

  // ---- two-level shfl exclusive scan over 1024 counts ----
  const int own = lhist[tid];
  const int wv = tid >> 6, ln = tid & 63;
  int sc = own;
  #pragma unroll
  for (int off = 1; off < 64; off <<= 1) {
    const int v = __shfl_up(sc, off, 64);
    if (ln >= off) sc += v;
  }
  if (ln == 63) wsum[wv] = sc;            // wave totals
  __syncthreads();
  if (tid < 64) {
    int tw = (tid < 16) ? wsum[tid] : 0;
    #pragma unroll
    for (int off = 1; off < 16; off <<= 1) {
      const int v = __shfl_up(tw, off, 64);
      if (tid >= off) tw += v;
    }
    if (tid < 16) wsum[tid] = tw;          // inclusive wave prefix
  }
  __syncthreads();
  const int excl = sc - own + (wv ? wsum[wv - 1] : 0);
  lcur[tid] = excl;
  offT[blockIdx.x * (kBuckets + 1) + tid] = excl;          // coalesced
  if (tid == 0) offT[blockIdx.x * (kBuckets + 1) + kBuckets] = cnt;
  __syncthreads();

  // ---- rank + scatter into this block's bucket-grouped region ----
  int* myBin = binned + blockIdx.x * kEdgesPerBlock;
  #pragma unroll
  for (int k = 0; k < kEPT; ++k) {
    const int j = tid + k * 1024;
    if (j < cnt) {
      const int pos = atomicAdd(&lcur[ebk[k]], 1);  // LDS int atomic
      myBin[pos] = es[k] | (edl[k] << 17);
    }
  }
}

// ---------------------------------------------------------------------------
// Kernel 2: one block per bucket (1024 blocks = 2 full occupancy rounds),
// 1024 threads (16 waves), 2 blocks/CU. (r22 structure; phase 4 now 4-deep
// software-pipelined.)
// ---------------------------------------------------------------------------
__global__ __launch_bounds__(1024, 8) void gcn_aggregate(
    const int*   __restrict__ ws_in,
    const float* __restrict__ W,     // [64][64] row-major W[o][d]
    const float* __restrict__ b,     // [64]
    float*       __restrict__ out) { // [kNodes][64]
  const uint2* fb16 = (const uint2*)(ws_in + kWsFeat);
  const int* offT   = ws_in + kWsOff;
  const int* binned = ws_in + kWsBinned;

  // lsrc (8KB, phases 1-4) and hsAll (16.1KB, phases 5-6) share storage.
  __shared__ __align__(16) char uShared[112 * 72 * 2];   // 16128 B
  __shared__ int    accum[kBucketNodes * kAccStride];    // 26.7 KB fixed-point
  __shared__ int    deg[128];                            // per-dL degree
  __shared__ int    wcur[128];                           // window hist -> cur
  __shared__ int    runL[kBinBlocks + 1];
  __shared__ int    runG[kBinBlocks];
  __shared__ int    ssm[kBinBlocks];
  __shared__ ushort Wb16[64 * 64];                 // 8 KB, natural W[o][d]
  __shared__ float  bsh[64];
  int*    lsrc  = (int*)uShared;
  ushort* hsAll = (ushort*)uShared;

  const int tid = threadIdx.x;
  const int bkt = blockIdx.x;

  if (tid < 128) { deg[tid] = 0; wcur[tid] = 0; }
  for (int i = tid; i < 4096; i += 1024) Wb16[i] = (ushort)bf16rne(W[i]);
  if (tid < 64) bsh[tid] = b[tid];
  for (int i = tid; i < kBucketNodes * kAccStride; i += 1024) accum[i] = 0;

  // ---- 0) segment map over the 256 block regions ----
  if (tid < kBinBlocks) {
    const int o0 = offT[tid * (kBuckets + 1) + bkt];
    const int o1 = offT[tid * (kBuckets + 1) + bkt + 1];
    runG[tid] = tid * kEdgesPerBlock + o0;
    ssm[tid] = o1 - o0;
  }
  __syncthreads();
  if (tid < 64) {                        // wave-0 shfl scan, 4 elems/lane
    const int base = tid * 4;
    const int v0 = ssm[base], v1 = ssm[base + 1];
    const int v2 = ssm[base + 2], v3 = ssm[base + 3];
    const int p1 = v0 + v1, p2 = p1 + v2, tot = p2 + v3;
    int sc = tot;
    #pragma unroll
    for (int off = 1; off < 64; off <<= 1) {
      const int v = __shfl_up(sc, off, 64);
      if (tid >= off) sc += v;
    }
    const int ex = sc - tot;             // exclusive prefix of lane total
    runL[base]     = ex;
    runL[base + 1] = ex + v0;
    runL[base + 2] = ex + p1;
    runL[base + 3] = ex + p2;
    if (tid == 63) runL[kBinBlocks] = sc;
  }
  __syncthreads();

  int sz = runL[kBinBlocks];
  if (sz > kCap) sz = kCap;  // never hit for this dataset

  // j -> global binned index via 8-step binary search over runL
  auto mapRead = [&](int j) -> unsigned {
    int lo = 0, hi = kBinBlocks;
    #pragma unroll
    for (int it = 0; it < 8; ++it) {
      const int mid = (lo + hi) >> 1;
      if (runL[mid] <= j) lo = mid; else hi = mid;
    }
    return (unsigned)binned[runG[lo] + (j - runL[lo])];
  };

  // ---- 1) dual histogram (degree + src-window); cache edge words ----
  const int j0 = tid, j1 = tid + 1024;
  const bool va = j0 < sz, vb = j1 < sz;
  unsigned ea = 0, eb = 0;
  if (va) {
    ea = mapRead(j0);
    atomicAdd(&deg[ea >> 17], 1);
    atomicAdd(&wcur[(ea & 0x1FFFFu) >> 10], 1);
  }
  if (vb) {
    eb = mapRead(j1);
    atomicAdd(&deg[eb >> 17], 1);
    atomicAdd(&wcur[(eb & 0x1FFFFu) >> 10], 1);
  }
  __syncthreads();

  // ---- 2) exclusive scan of 128 window counters by wave 0 (98 live) ----
  if (tid < 64) {
    const int a  = wcur[tid * 2];
    const int b2 = wcur[tid * 2 + 1];
    int s = a + b2;
    #pragma unroll
    for (int off = 1; off < 64; off <<= 1) {
      const int v = __shfl_up(s, off, 64);
      if (tid >= off) s += v;
    }
    const int ex1 = s - b2;
    const int ex0 = ex1 - a;
    wcur[tid * 2]     = ex0;
    wcur[tid * 2 + 1] = ex1;
  }
  __syncthreads();

  // ---- 3) rank + scatter grouped by src-window (ascending src sweep) ----
  if (va) { const int p = atomicAdd(&wcur[(ea & 0x1FFFFu) >> 10], 1); lsrc[p] = (int)ea; }
  if (vb) { const int p = atomicAdd(&wcur[(eb & 0x1FFFFu) >> 10], 1); lsrc[p] = (int)eb; }
  __syncthreads();

  // ---- 4) lane-strided sweep gather, 4-deep pipelined, LDS atomics ----
  const int wave = tid >> 6;
  const int lane = tid & 63;
  const int g = lane >> 4;   // slot within wave
  const int c = lane & 15;   // 8B chunk = feats {c,16+c,32+c,48+c}
  {
    const int slot = wave * 4 + g;           // 0..63
    int j = slot;
    // 4-deep batches: 4 independent lsrc reads -> 4 independent gathers ->
    // 16 fixed-point atomics. Doubles MLP vs unroll-2.
    for (; j + 192 < sz; j += 256) {
      const unsigned e0 = (unsigned)lsrc[j];
      const unsigned e1 = (unsigned)lsrc[j + 64];
      const unsigned e2 = (unsigned)lsrc[j + 128];
      const unsigned e3 = (unsigned)lsrc[j + 192];
      const uint2 v0 = fb16[(size_t)(e0 & 0x1FFFFu) * 16 + c];
      const uint2 v1 = fb16[(size_t)(e1 & 0x1FFFFu) * 16 + c];
      const uint2 v2 = fb16[(size_t)(e2 & 0x1FFFFu) * 16 + c];
      const uint2 v3 = fb16[(size_t)(e3 & 0x1FFFFu) * 16 + c];
      int* r0 = accum + (int)(e0 >> 17) * kAccStride + c;
      atomicAdd(r0 + 0,  (int)(__uint_as_float(v0.x << 16)          * kFxScale));
      atomicAdd(r0 + 16, (int)(__uint_as_float(v0.x & 0xffff0000u) * kFxScale));
      atomicAdd(r0 + 32, (int)(__uint_as_float(v0.y << 16)          * kFxScale));
      atomicAdd(r0 + 48, (int)(__uint_as_float(v0.y & 0xffff0000u) * kFxScale));
      int* r1 = accum + (int)(e1 >> 17) * kAccStride + c;
      atomicAdd(r1 + 0,  (int)(__uint_as_float(v1.x << 16)          * kFxScale));
      atomicAdd(r1 + 16, (int)(__uint_as_float(v1.x & 0xffff0000u) * kFxScale));
      atomicAdd(r1 + 32, (int)(__uint_as_float(v1.y << 16)          * kFxScale));
      atomicAdd(r1 + 48, (int)(__uint_as_float(v1.y & 0xffff0000u) * kFxScale));
      int* r2 = accum + (int)(e2 >> 17) * kAccStride + c;
      atomicAdd(r2 + 0,  (int)(__uint_as_float(v2.x << 16)          * kFxScale));
      atomicAdd(r2 + 16, (int)(__uint_as_float(v2.x & 0xffff0000u) * kFxScale));
      atomicAdd(r2 + 32, (int)(__uint_as_float(v2.y << 16)          * kFxScale));
      atomicAdd(r2 + 48, (int)(__uint_as_float(v2.y & 0xffff0000u) * kFxScale));
      int* r3 = accum + (int)(e3 >> 17) * kAccStride + c;
      atomicAdd(r3 + 0,  (int)(__uint_as_float(v3.x << 16)          * kFxScale));
      atomicAdd(r3 + 16, (int)(__uint_as_float(v3.x & 0xffff0000u) * kFxScale));
      atomicAdd(r3 + 32, (int)(__uint_as_float(v3.y << 16)          * kFxScale));
      atomicAdd(r3 + 48, (int)(__uint_as_float(v3.y & 0xffff0000u) * kFxScale));
    }
    for (; j < sz; j += 64) {               // remainder, <=3 per slot
      const unsigned e = (unsigned)lsrc[j];
      const uint2 v = fb16[(size_t)(e & 0x1FFFFu) * 16 + c];
      int* rp = accum + (int)(e >> 17) * kAccStride + c;
      atomicAdd(rp + 0,  (int)(__uint_as_float(v.x << 16)          * kFxScale));
      atomicAdd(rp + 16, (int)(__uint_as_float(v.x & 0xffff0000u) * kFxScale));
      atomicAdd(rp + 32, (int)(__uint_as_float(v.y << 16)          * kFxScale));
      atomicAdd(rp + 48, (int)(__uint_as_float(v.y & 0xffff0000u) * kFxScale));
    }
  }
  __syncthreads();

  // ---- 5) accum -> bf16 mean rows via deg[] (over dead lsrc) ----
  {
    const int nd = tid >> 3;          // 0..127; 98 live rows, 8 chunks each
    const int ch = tid & 7;
    if (nd < kBucketNodes) {
      const int dg = deg[nd];
      const float inv = 1.0f / (kFxScale * (float)(dg > 1 ? dg : 1));
      const int* arow = accum + nd * kAccStride + ch * 8;
      unsigned h[8];
      #pragma unroll
      for (int q = 0; q < 8; ++q) h[q] = bf16rne((float)arow[q] * inv);
      uint4 pk;
      pk.x = h[0] | (h[1] << 16);
      pk.y = h[2] | (h[3] << 16);
      pk.z = h[4] | (h[5] << 16);
      pk.w = h[6] | (h[7] << 16);
      *(uint4*)(hsAll + nd * 72 + ch * 8) = pk;
    } else {
      if (nd < 112) *(uint4*)(hsAll + nd * 72 + ch * 8) =
          make_uint4(0u, 0u, 0u, 0u);
    }
  }
  __syncthreads();

  // ---- 6) MFMA epilogue (waves 0..6): wave w -> locals [w*16, w*16+16) ----
  if (tid < 448) {
    const int w8   = tid >> 6;        // 0..6
    const int ln   = tid & 63;
    const int quad = ln >> 4;
    const int col  = ln & 15;
    const int n0 = bkt * kBucketNodes;

    const short8 af0 = *reinterpret_cast<const short8*>(
        hsAll + (w8 * 16 + col) * 72 + 0 * 32 + quad * 8);
    const short8 af1 = *reinterpret_cast<const short8*>(
        hsAll + (w8 * 16 + col) * 72 + 1 * 32 + quad * 8);

    #pragma unroll
    for (int ob = 0; ob < 4; ++ob) {
      const short8 bf0 = *reinterpret_cast<const short8*>(
          Wb16 + (ob * 16 + col) * 64 + 0 * 32 + quad * 8);
      const short8 bf1 = *reinterpret_cast<const short8*>(
          Wb16 + (ob * 16 + col) * 64 + 1 * 32 + quad * 8);
      floatx4 acc = {0.f, 0.f, 0.f, 0.f};
      acc = __builtin_amdgcn_mfma_f32_16x16x32_bf16(af0, bf0, acc, 0, 0, 0);
      acc = __builtin_amdgcn_mfma_f32_16x16x32_bf16(af1, bf1, acc, 0, 0, 0);

      const int o = ob * 16 + col;
      const float bo = bsh[o];
      #pragma unroll
      for (int r = 0; r < 4; ++r) {
        const int local = w8 * 16 + quad * 4 + r;
        const int node = n0 + local;
        if (local < kBucketNodes && node < kNodes) {
          const float v = acc[r] + bo;
          out[(size_t)node * 64 + o] = v > 0.0f ? v : 0.0f;
        }
      }
    }
  }
}

// ---------------------------------------------------------------------------
extern "C" void kernel_launch(void* const* d_in, const int* in_sizes, int n_in,
                              void* d_out, int out_size, void* d_ws, size_t ws_size,
                              hipStream_t stream) {
  const float* feature  = (const float*)d_in[0];
  const int*   edge_src = (const int*)  d_in[1];
  const int*   edge_dst = (const int*)  d_in[2];
  const float* W        = (const float*)d_in[3];
  const float* b        = (const float*)d_in[4];

  float* out = (float*)d_out;
  int*   ws  = (int*)d_ws;

  gcn_build<<<kBinBlocks, 1024, 0, stream>>>(feature, edge_src, edge_dst, ws);
  gcn_aggregate<<<kBuckets, 1024, 0, stream>>>(ws, W, b, out);
}